// Round 2
// baseline (939.787 us; speedup 1.0000x reference)
//
#include <hip/hip_runtime.h>

#define HN 64
#define WN 64
#define HW 4096
#define CIN 256
#define COUT 256
#define NB 8
#define NKK 9
#define OFFC 18
#define KTOT (CIN*NKK)   // 2304

// ---------------- Stage 1: offsets = conv3x3(x, w_off) + b_off -------------
// grid: 8 b * 64 tiles (8x8). 256 threads: 64 px * 4-way ci split + LDS reduce.
__global__ __launch_bounds__(256) void offs_conv_kernel(
    const float* __restrict__ x, const float* __restrict__ w_off,
    const float* __restrict__ b_off, float* __restrict__ offs)
{
    __shared__ float red[4][64][OFFC];   // 18432 B
    const int blk = blockIdx.x;
    const int b = blk >> 6;
    const int tile = blk & 63;
    const int ty0 = (tile >> 3) << 3;
    const int tx0 = (tile & 7) << 3;
    const int t = threadIdx.x;
    const int p = t & 63;
    const int cq = t >> 6;
    const int py = ty0 + (p >> 3);
    const int px = tx0 + (p & 7);

    float acc[OFFC];
#pragma unroll
    for (int c = 0; c < OFFC; ++c) acc[c] = 0.f;

    const float* xb = x + (size_t)b * CIN * HW;
    for (int ci = cq * 64; ci < cq * 64 + 64; ++ci) {
        const float* xc = xb + (size_t)ci * HW;
        float xv[9];
#pragma unroll
        for (int ky = 0; ky < 3; ++ky) {
            const int yy = py + ky - 1;
#pragma unroll
            for (int kx = 0; kx < 3; ++kx) {
                const int xx = px + kx - 1;
                xv[ky*3+kx] = ((unsigned)yy < HN && (unsigned)xx < WN) ? xc[yy*WN + xx] : 0.f;
            }
        }
        const float* wp = w_off + (size_t)ci * NKK;
#pragma unroll
        for (int c = 0; c < OFFC; ++c)
#pragma unroll
            for (int k = 0; k < NKK; ++k)
                acc[c] = fmaf(xv[k], wp[(size_t)c * KTOT + k], acc[c]);
    }
#pragma unroll
    for (int c = 0; c < OFFC; ++c) red[cq][p][c] = acc[c];
    __syncthreads();
    for (int idx = t; idx < 64 * OFFC; idx += 256) {
        const int c = idx >> 6;        // 0..17 over two passes (1152/256=4.5)
        const int pp = idx & 63;
        const float v = red[0][pp][c] + red[1][pp][c] + red[2][pp][c] + red[3][pp][c] + b_off[c];
        offs[((size_t)b * OFFC + c) * HW + (ty0 + (pp >> 3)) * WN + tx0 + (pp & 7)] = v;
    }
}

// ---------------- Stage 2: bilinear gather + 3x3 conv (the big GEMM) -------
#define CICH 16
#define KCH (CICH*NKK)   // 144

__global__ __launch_bounds__(256) void dcn_kernel(
    const float* __restrict__ x, const float* __restrict__ offs,
    const float* __restrict__ w, const float* __restrict__ bias,
    float* __restrict__ out)
{
    __shared__ float samp[KCH][64];    // 36864 B
    __shared__ int   tidx[576][4];     //  9216 B
    __shared__ float twgt[576][4];     //  9216 B

    const int blk = blockIdx.x;        // 8 b * 64 tiles
    const int b = blk >> 6;
    const int tile = blk & 63;
    const int ty0 = (tile >> 3) << 3;
    const int tx0 = (tile & 7) << 3;
    const int t = threadIdx.x;

    // tap precompute: 576 = 64 px * 9 taps
    for (int i = t; i < 576; i += 256) {
        const int p = i / 9, kk = i - 9 * (i / 9);
        const int oy = ty0 + (p >> 3), ox = tx0 + (p & 7);
        const float offy = offs[((size_t)b * OFFC + 2 * kk    ) * HW + oy * WN + ox];
        const float offx = offs[((size_t)b * OFFC + 2 * kk + 1) * HW + oy * WN + ox];
        const float pyf = (float)(oy - 1 + kk / 3) + offy;
        const float pxf = (float)(ox - 1 + kk % 3) + offx;
        const float fy0 = floorf(pyf), fx0 = floorf(pxf);
        const int iy0 = (int)fy0, ix0 = (int)fx0;
        const int iy1 = iy0 + 1, ix1 = ix0 + 1;
        const float fy = pyf - fy0, fx = pxf - fx0;
        const float vy0 = ((unsigned)iy0 < HN) ? 1.f : 0.f;
        const float vy1 = ((unsigned)iy1 < HN) ? 1.f : 0.f;
        const float vx0 = ((unsigned)ix0 < WN) ? 1.f : 0.f;
        const float vx1 = ((unsigned)ix1 < WN) ? 1.f : 0.f;
        const int cy0 = min(max(iy0, 0), HN - 1), cy1 = min(max(iy1, 0), HN - 1);
        const int cx0 = min(max(ix0, 0), WN - 1), cx1 = min(max(ix1, 0), WN - 1);
        tidx[i][0] = cy0 * WN + cx0; tidx[i][1] = cy0 * WN + cx1;
        tidx[i][2] = cy1 * WN + cx0; tidx[i][3] = cy1 * WN + cx1;
        twgt[i][0] = (1.f - fy) * (1.f - fx) * vy0 * vx0;
        twgt[i][1] = (1.f - fy) * fx * vy0 * vx1;
        twgt[i][2] = fy * (1.f - fx) * vy1 * vx0;
        twgt[i][3] = fy * fx * vy1 * vx1;
    }

    const int px_g = t & 7;     // pixel row of tile
    const int co_g = t >> 3;    // 32 groups of 8 output channels
    float acc[8][8];
#pragma unroll
    for (int i = 0; i < 8; ++i)
#pragma unroll
        for (int j = 0; j < 8; ++j) acc[i][j] = 0.f;

    for (int ci0 = 0; ci0 < CIN; ci0 += CICH) {
        __syncthreads();   // also covers tap-precompute on first iteration
        // sampling: fill samp[144][64]
        for (int s = t; s < KCH * 64; s += 256) {
            const int r = s >> 6, p = s & 63;
            const int cic = r / 9, kk = r - 9 * cic;
            const float* xc = x + ((size_t)(b * CIN + ci0 + cic)) * HW;
            const int ti = p * 9 + kk;
            samp[r][p] = twgt[ti][0] * xc[tidx[ti][0]] + twgt[ti][1] * xc[tidx[ti][1]]
                       + twgt[ti][2] * xc[tidx[ti][2]] + twgt[ti][3] * xc[tidx[ti][3]];
        }
        __syncthreads();
        // GEMM phase: 8 co x 8 px register tile per thread
        const float* wp = w + (size_t)ci0 * NKK;
        for (int r = 0; r < KCH; r += 4) {
            float sv[4][8];
#pragma unroll
            for (int rr = 0; rr < 4; ++rr) {
                *(float4*)&sv[rr][0] = *(const float4*)&samp[r + rr][px_g * 8];
                *(float4*)&sv[rr][4] = *(const float4*)&samp[r + rr][px_g * 8 + 4];
            }
#pragma unroll
            for (int i = 0; i < 8; ++i) {
                const float4 wv = *(const float4*)&wp[(size_t)(co_g * 8 + i) * KTOT + r];
                const float wa[4] = {wv.x, wv.y, wv.z, wv.w};
#pragma unroll
                for (int rr = 0; rr < 4; ++rr)
#pragma unroll
                    for (int j = 0; j < 8; ++j)
                        acc[i][j] = fmaf(wa[rr], sv[rr][j], acc[i][j]);
            }
        }
    }

    // epilogue
    const int oy = ty0 + px_g;
    float* op = out + ((size_t)b * COUT + co_g * 8) * HW + oy * WN + tx0;
#pragma unroll
    for (int i = 0; i < 8; ++i) {
        const float bv = bias[co_g * 8 + i];
        float4 v0 = {acc[i][0] + bv, acc[i][1] + bv, acc[i][2] + bv, acc[i][3] + bv};
        float4 v1 = {acc[i][4] + bv, acc[i][5] + bv, acc[i][6] + bv, acc[i][7] + bv};
        *(float4*)(op + (size_t)i * HW) = v0;
        *(float4*)(op + (size_t)i * HW + 4) = v1;
    }
}

extern "C" void kernel_launch(void* const* d_in, const int* in_sizes, int n_in,
                              void* d_out, int out_size, void* d_ws, size_t ws_size,
                              hipStream_t stream) {
    const float* x     = (const float*)d_in[0];
    const float* w_off = (const float*)d_in[1];
    const float* b_off = (const float*)d_in[2];
    const float* w_dcn = (const float*)d_in[3];
    const float* b_dcn = (const float*)d_in[4];
    float* out  = (float*)d_out;
    float* offs = (float*)d_ws;   // 8*18*4096 fp32 = 2.36 MB

    offs_conv_kernel<<<512, 256, 0, stream>>>(x, w_off, b_off, offs);
    dcn_kernel<<<512, 256, 0, stream>>>(x, offs, w_dcn, b_dcn, out);
}

// Round 3
// 471.832 us; speedup vs baseline: 1.9918x; 1.9918x over previous
//
#include <hip/hip_runtime.h>

#define HN 64
#define WN 64
#define HW 4096
#define CIN 256
#define COUT 256
#define NKK 9
#define OFFC 18
#define KTOT (CIN*NKK)     // 2304
#define CICH 32
#define KCH (CICH*NKK)     // 288 k-rows per chunk
#define SROW (KCH+8)       // 296 bf16 -> 592 B row stride (16B-aligned, 2-way-free reads)
#define NCHUNK (CIN/CICH)  // 8

typedef __attribute__((ext_vector_type(8))) short bf16x8;
typedef __attribute__((ext_vector_type(4))) float f32x4;

// fp32 -> bf16 with round-to-nearest-even (bit version; inputs finite)
static __device__ __forceinline__ unsigned short f2bf(float f) {
    unsigned u = __float_as_uint(f);
    return (unsigned short)((u + 0x7FFFu + ((u >> 16) & 1u)) >> 16);
}
static __device__ __forceinline__ unsigned pk2(float a, float b) {
    return (unsigned)f2bf(a) | ((unsigned)f2bf(b) << 16);
}

// ---------------- Stage 0: pack weights to bf16 in workspace ---------------
// blocks 0..287: w_dcn (256*2304 = 589824 elems). blocks 288..323: w_off padded
// to 32 rows (32*2304 = 73728 elems; rows >=18 are zero).
__global__ __launch_bounds__(256) void cvt_kernel(
    const float* __restrict__ w_dcn, const float* __restrict__ w_off,
    unsigned short* __restrict__ wd_b, unsigned short* __restrict__ wo_b)
{
    const int blk = blockIdx.x;
    const int t = threadIdx.x;
    if (blk < 288) {
        const int i = blk * 2048 + t * 8;
        const float4 f0 = *(const float4*)(w_dcn + i);
        const float4 f1 = *(const float4*)(w_dcn + i + 4);
        uint4 o = { pk2(f0.x, f0.y), pk2(f0.z, f0.w), pk2(f1.x, f1.y), pk2(f1.z, f1.w) };
        *(uint4*)(wd_b + i) = o;
    } else {
        const int i = (blk - 288) * 2048 + t * 8;
        float v[8];
#pragma unroll
        for (int j = 0; j < 8; ++j)
            v[j] = (i + j < OFFC * KTOT) ? w_off[i + j] : 0.f;
        uint4 o = { pk2(v[0], v[1]), pk2(v[2], v[3]), pk2(v[4], v[5]), pk2(v[6], v[7]) };
        *(uint4*)(wo_b + i) = o;
    }
}

// ---------------- Stage 1: offsets conv via im2col + MFMA ------------------
// grid 512 = 8 b * 64 tiles(8x8). 4 waves: all stage; wave w owns px-tile w,
// 2 cout-tiles (rows 0..15, 16..31; only c<18 written).
__global__ __launch_bounds__(256) void offs_mfma_kernel(
    const float* __restrict__ x, const unsigned short* __restrict__ wo_b,
    const float* __restrict__ b_off, float* __restrict__ offs)
{
    __shared__ unsigned short samp[64 * SROW];   // 37,888 B  [px][k]
    const int blk = blockIdx.x;
    const int b = blk >> 6;
    const int tile = blk & 63;
    const int ty0 = (tile >> 3) << 3;
    const int tx0 = (tile & 7) << 3;
    const int t = threadIdx.x;
    const int lane = t & 63;
    const int wave = t >> 6;
    const int oy = ty0 + (lane >> 3);
    const int ox = tx0 + (lane & 7);

    f32x4 acc0 = {0.f, 0.f, 0.f, 0.f}, acc1 = {0.f, 0.f, 0.f, 0.f};

    for (int chunk = 0; chunk < NCHUNK; ++chunk) {
        const int ci0 = chunk * CICH;
        __syncthreads();
        // staging: im2col, 9 k-groups of 8 per wave, lanes = 64 px
        for (int i = 0; i < 9; ++i) {
            const int g = wave * 9 + i;
            const int k0 = g * 8;
            int cic = k0 / 9;
            int kk = k0 - cic * 9;
            const float* xc = x + ((size_t)(b * CIN + ci0 + cic)) * HW;
            float v[8];
#pragma unroll
            for (int j = 0; j < 8; ++j) {
                const int yy = oy - 1 + kk / 3;
                const int xx = ox - 1 + kk % 3;
                v[j] = ((unsigned)yy < HN && (unsigned)xx < WN) ? xc[yy * WN + xx] : 0.f;
                if (++kk == 9) { kk = 0; xc += HW; }
            }
            uint4 o = { pk2(v[0], v[1]), pk2(v[2], v[3]), pk2(v[4], v[5]), pk2(v[6], v[7]) };
            *(uint4*)&samp[lane * SROW + k0] = o;
        }
        __syncthreads();
        // GEMM: M=32 (cout, padded), N=16 px (this wave's tile), K=288
        const unsigned short* wb = wo_b + (size_t)(lane & 15) * KTOT + ci0 * NKK + (lane >> 4) * 8;
        const unsigned short* sb = &samp[(wave * 16 + (lane & 15)) * SROW + (lane >> 4) * 8];
        for (int s = 0; s < 9; ++s) {
            const bf16x8 bfr = *(const bf16x8*)(sb + s * 32);
            const bf16x8 a0 = *(const bf16x8*)(wb + s * 32);
            const bf16x8 a1 = *(const bf16x8*)(wb + 16 * KTOT + s * 32);
            acc0 = __builtin_amdgcn_mfma_f32_16x16x32_bf16(a0, bfr, acc0, 0, 0, 0);
            acc1 = __builtin_amdgcn_mfma_f32_16x16x32_bf16(a1, bfr, acc1, 0, 0, 0);
        }
    }
    // epilogue: D[c][px], col = lane&15 = px-in-tile, row = (lane>>4)*4+j
    const int px = wave * 16 + (lane & 15);
    const int wy = ty0 + (px >> 3), wx = tx0 + (px & 7);
#pragma unroll
    for (int j = 0; j < 4; ++j) {
        const int c0 = (lane >> 4) * 4 + j;
        if (c0 < OFFC)
            offs[((size_t)b * OFFC + c0) * HW + wy * WN + wx] = acc0[j] + b_off[c0];
        const int c1 = 16 + c0;
        if (c1 < OFFC)
            offs[((size_t)b * OFFC + c1) * HW + wy * WN + wx] = acc1[j] + b_off[c1];
    }
}

// ---------------- Stage 2: bilinear gather + MFMA GEMM ---------------------
// grid 512. 4 waves: all stage cooperatively; wave w owns cout [w*64,w*64+64)
// x all 64 px: acc[4 cout-tiles][4 px-tiles] of f32x4 (64 VGPR).
__global__ __launch_bounds__(256) void dcn_mfma_kernel(
    const float* __restrict__ x, const float* __restrict__ offs,
    const unsigned short* __restrict__ wd_b, const float* __restrict__ bias,
    float* __restrict__ out)
{
    __shared__ unsigned short samp[64 * SROW];   // 37,888 B  [px][k]
    __shared__ uint4  tidx[9 * 64];              //  9,216 B  [kk][px]
    __shared__ float4 twgt[9 * 64];              //  9,216 B  [kk][px]

    const int blk = blockIdx.x;
    const int b = blk >> 6;
    const int tile = blk & 63;
    const int ty0 = (tile >> 3) << 3;
    const int tx0 = (tile & 7) << 3;
    const int t = threadIdx.x;
    const int lane = t & 63;
    const int wave = t >> 6;

    // tap precompute: i = kk*64 + px
    for (int i = t; i < 576; i += 256) {
        const int kk = i >> 6, p = i & 63;
        const int oy = ty0 + (p >> 3), ox = tx0 + (p & 7);
        const float offy = offs[((size_t)b * OFFC + 2 * kk) * HW + oy * WN + ox];
        const float offx = offs[((size_t)b * OFFC + 2 * kk + 1) * HW + oy * WN + ox];
        const float pyf = (float)(oy - 1 + kk / 3) + offy;
        const float pxf = (float)(ox - 1 + kk % 3) + offx;
        const float fy0 = floorf(pyf), fx0 = floorf(pxf);
        const int iy0 = (int)fy0, ix0 = (int)fx0;
        const int iy1 = iy0 + 1, ix1 = ix0 + 1;
        const float fy = pyf - fy0, fx = pxf - fx0;
        const float vy0 = ((unsigned)iy0 < HN) ? 1.f : 0.f;
        const float vy1 = ((unsigned)iy1 < HN) ? 1.f : 0.f;
        const float vx0 = ((unsigned)ix0 < WN) ? 1.f : 0.f;
        const float vx1 = ((unsigned)ix1 < WN) ? 1.f : 0.f;
        const int cy0 = min(max(iy0, 0), HN - 1), cy1 = min(max(iy1, 0), HN - 1);
        const int cx0 = min(max(ix0, 0), WN - 1), cx1 = min(max(ix1, 0), WN - 1);
        tidx[i] = make_uint4(cy0 * WN + cx0, cy0 * WN + cx1, cy1 * WN + cx0, cy1 * WN + cx1);
        twgt[i] = make_float4((1.f - fy) * (1.f - fx) * vy0 * vx0,
                              (1.f - fy) * fx * vy0 * vx1,
                              fy * (1.f - fx) * vy1 * vx0,
                              fy * fx * vy1 * vx1);
    }

    f32x4 acc[4][4];
#pragma unroll
    for (int i = 0; i < 4; ++i)
#pragma unroll
        for (int j = 0; j < 4; ++j) acc[i][j] = (f32x4){0.f, 0.f, 0.f, 0.f};

    const int c0 = wave * 64;

    for (int chunk = 0; chunk < NCHUNK; ++chunk) {
        const int ci0 = chunk * CICH;
        __syncthreads();   // covers tap precompute (1st iter) + prev GEMM readers
        // staging: 9 k-groups of 8 per wave; lanes = 64 px (coalesced gathers)
        for (int i = 0; i < 9; ++i) {
            const int g = wave * 9 + i;
            const int k0 = g * 8;
            int cic = k0 / 9;
            int kk = k0 - cic * 9;
            const float* xc = x + ((size_t)(b * CIN + ci0 + cic)) * HW;
            float v[8];
#pragma unroll
            for (int j = 0; j < 8; ++j) {
                const uint4 ti = tidx[kk * 64 + lane];
                const float4 tw = twgt[kk * 64 + lane];
                v[j] = tw.x * xc[ti.x] + tw.y * xc[ti.y] + tw.z * xc[ti.z] + tw.w * xc[ti.w];
                if (++kk == 9) { kk = 0; xc += HW; }
            }
            uint4 o = { pk2(v[0], v[1]), pk2(v[2], v[3]), pk2(v[4], v[5]), pk2(v[6], v[7]) };
            *(uint4*)&samp[lane * SROW + k0] = o;
        }
        __syncthreads();
        // GEMM: A = W rows (global bf16), B = samp (LDS), D[cout][px]
        const unsigned short* wb = wd_b + (size_t)(c0 + (lane & 15)) * KTOT + ci0 * NKK + (lane >> 4) * 8;
        const unsigned short* sb = &samp[(lane & 15) * SROW + (lane >> 4) * 8];
        for (int s = 0; s < 9; ++s) {
            bf16x8 afr[4], bfr[4];
#pragma unroll
            for (int ct = 0; ct < 4; ++ct)
                afr[ct] = *(const bf16x8*)(wb + (size_t)ct * 16 * KTOT + s * 32);
#pragma unroll
            for (int pt = 0; pt < 4; ++pt)
                bfr[pt] = *(const bf16x8*)(sb + pt * 16 * SROW + s * 32);
#pragma unroll
            for (int ct = 0; ct < 4; ++ct)
#pragma unroll
                for (int pt = 0; pt < 4; ++pt)
                    acc[ct][pt] = __builtin_amdgcn_mfma_f32_16x16x32_bf16(afr[ct], bfr[pt], acc[ct][pt], 0, 0, 0);
        }
    }

    // epilogue: lane holds D[cout=(lane>>4)*4+j][px=lane&15] per (ct,pt) tile
#pragma unroll
    for (int ct = 0; ct < 4; ++ct) {
#pragma unroll
        for (int pt = 0; pt < 4; ++pt) {
            const int px = pt * 16 + (lane & 15);
            const int wy = ty0 + (px >> 3), wx = tx0 + (px & 7);
#pragma unroll
            for (int j = 0; j < 4; ++j) {
                const int cout = c0 + ct * 16 + (lane >> 4) * 4 + j;
                out[((size_t)b * COUT + cout) * HW + wy * WN + wx] = acc[ct][pt][j] + bias[cout];
            }
        }
    }
}

extern "C" void kernel_launch(void* const* d_in, const int* in_sizes, int n_in,
                              void* d_out, int out_size, void* d_ws, size_t ws_size,
                              hipStream_t stream) {
    const float* x     = (const float*)d_in[0];
    const float* w_off = (const float*)d_in[1];
    const float* b_off = (const float*)d_in[2];
    const float* w_dcn = (const float*)d_in[3];
    const float* b_dcn = (const float*)d_in[4];
    float* out = (float*)d_out;

    // ws layout: offs fp32 (2,359,296 B) | w_dcn bf16 (1,179,648 B) | w_off bf16 pad32 (147,456 B)
    float* offs = (float*)d_ws;
    unsigned short* wd_b = (unsigned short*)((char*)d_ws + 2359296);
    unsigned short* wo_b = (unsigned short*)((char*)d_ws + 2359296 + 1179648);

    cvt_kernel<<<324, 256, 0, stream>>>(w_dcn, w_off, wd_b, wo_b);
    offs_mfma_kernel<<<512, 256, 0, stream>>>(x, wo_b, b_off, offs);
    dcn_mfma_kernel<<<512, 256, 0, stream>>>(x, offs, wd_b, b_dcn, out);
}

// Round 5
// 235.395 us; speedup vs baseline: 3.9924x; 2.0044x over previous
//
#include <hip/hip_runtime.h>

#define HN 64
#define WN 64
#define HW 4096
#define CIN 256
#define COUT 256
#define NKK 9
#define OFFC 18
#define KTOT 2304          // 256*9, reordered kk-major: k = kk*256 + c
#define CICH 32
#define KCH 288            // k-rows per chunk (9 kk * 32 c)
#define SROW 296           // samp row stride in bf16 (288 + 8 pad, 592 B)
#define NCHUNK 8

typedef __attribute__((ext_vector_type(8))) short bf16x8;
typedef __attribute__((ext_vector_type(4))) float f32x4;

// fp32 -> bf16 round-to-nearest-even (finite inputs)
static __device__ __forceinline__ unsigned short f2bf(float f) {
    unsigned u = __float_as_uint(f);
    return (unsigned short)((u + 0x7FFFu + ((u >> 16) & 1u)) >> 16);
}
static __device__ __forceinline__ unsigned pk2(float a, float b) {
    return (unsigned)f2bf(a) | ((unsigned)f2bf(b) << 16);
}
static __device__ __forceinline__ float bf2f(short s) {
    return __uint_as_float(((unsigned)(unsigned short)s) << 16);
}

// ---------------- Stage 0: prep — x transpose to NHWC bf16 + weight repack --
// blocks 0..511   : xh[b][p][c] = bf16(x[b][c][p]); block = (b, H-row)
// blocks 512..767 : wd_b[cout][kk*256+c] = bf16(w_dcn[cout][c][kk])
// blocks 768..799 : wo_b[r][kk*256+c]    = bf16(w_off[r][c][kk]), rows 18..31 = 0
__global__ __launch_bounds__(256) void prep_kernel(
    const float* __restrict__ x, const float* __restrict__ w_dcn,
    const float* __restrict__ w_off, unsigned short* __restrict__ xh,
    unsigned short* __restrict__ wd_b, unsigned short* __restrict__ wo_b)
{
    const int blk = blockIdx.x;
    const int t = threadIdx.x;
    if (blk < 512) {
        __shared__ unsigned short lds[64 * 264];   // row pad 8 bf16
        const int b = blk >> 6;
        const int row = blk & 63;
        const int p = t & 63;
        const int cb = (t >> 6) * 8;
        const float* xp = x + (size_t)b * CIN * HW + row * WN + p;
#pragma unroll
        for (int i = 0; i < 8; ++i) {
            const int c0 = cb + i * 32;
            float v[8];
#pragma unroll
            for (int j = 0; j < 8; ++j)
                v[j] = xp[(size_t)(c0 + j) * HW];   // 64-lane coalesced per j
            uint4 o = { pk2(v[0],v[1]), pk2(v[2],v[3]), pk2(v[4],v[5]), pk2(v[6],v[7]) };
            *(uint4*)&lds[p * 264 + c0] = o;
        }
        __syncthreads();
        unsigned short* op = xh + ((size_t)b * HW + row * WN) * CIN;
#pragma unroll
        for (int i = 0; i < 8; ++i) {
            const int idx = i * 256 + t;
            const int cg = idx & 31, pp = idx >> 5;
            *(uint4*)(op + (size_t)pp * CIN + cg * 8) = *(const uint4*)&lds[pp * 264 + cg * 8];
        }
    } else if (blk < 768) {
        const int cout = blk - 512;
        for (int id = t; id < 288; id += 256) {
            const int k = id * 8;
            const int kk = k >> 8, c0 = k & 255;
            const float* wp = w_dcn + (size_t)cout * KTOT + kk;
            float v[8];
#pragma unroll
            for (int j = 0; j < 8; ++j) v[j] = wp[(size_t)(c0 + j) * NKK];
            uint4 o = { pk2(v[0],v[1]), pk2(v[2],v[3]), pk2(v[4],v[5]), pk2(v[6],v[7]) };
            *(uint4*)(wd_b + (size_t)cout * KTOT + k) = o;
        }
    } else {
        const int r = blk - 768;
        for (int id = t; id < 288; id += 256) {
            const int k = id * 8;
            const int kk = k >> 8, c0 = k & 255;
            uint4 o = {0u, 0u, 0u, 0u};
            if (r < OFFC) {
                const float* wp = w_off + (size_t)r * KTOT + kk;
                float v[8];
#pragma unroll
                for (int j = 0; j < 8; ++j) v[j] = wp[(size_t)(c0 + j) * NKK];
                o = (uint4){ pk2(v[0],v[1]), pk2(v[2],v[3]), pk2(v[4],v[5]), pk2(v[6],v[7]) };
            }
            *(uint4*)(wo_b + (size_t)r * KTOT + k) = o;
        }
    }
}

// ---------------- Stage 1: offsets conv via vector im2col + MFMA -----------
// 256 threads / 4 waves; wave w owns px-tile w (16 px), M=32 cout rows.
__global__ __launch_bounds__(256) void offs_mfma_kernel(
    const unsigned short* __restrict__ xh, const unsigned short* __restrict__ wo_b,
    const float* __restrict__ b_off, float* __restrict__ offs)
{
    __shared__ unsigned short samp[64 * SROW];   // 37,888 B  [px][k']
    const int blk = blockIdx.x;
    const int b = blk >> 6;
    const int tile = blk & 63;
    const int ty0 = (tile >> 3) << 3;
    const int tx0 = (tile & 7) << 3;
    const int t = threadIdx.x;
    const int lane = t & 63;
    const int wave = t >> 6;
    const unsigned short* xb = xh + (size_t)b * HW * CIN;

    f32x4 acc0 = {0.f,0.f,0.f,0.f}, acc1 = {0.f,0.f,0.f,0.f};

    for (int chunk = 0; chunk < NCHUNK; ++chunk) {
        const int ci0 = chunk * CICH;
        __syncthreads();
        // im2col staging: pure predicated 16B copies, k' = kk*32 + (c-ci0)
        for (int id = t; id < 2304; id += 256) {
            const int kk = id >> 8;
            const int px = (id >> 2) & 63;
            const int g = id & 3;
            const int ky = kk / 3;
            const int oy = ty0 + (px >> 3) + ky - 1;
            const int ox = tx0 + (px & 7) + (kk - ky * 3) - 1;
            bf16x8 v = {0,0,0,0,0,0,0,0};
            if ((unsigned)oy < HN && (unsigned)ox < WN)
                v = *(const bf16x8*)(xb + (size_t)(oy * WN + ox) * CIN + ci0 + g * 8);
            *(bf16x8*)&samp[px * SROW + kk * 32 + g * 8] = v;
        }
        __syncthreads();
        const unsigned short* wb = wo_b + (size_t)(lane & 15) * KTOT + ci0 + (lane >> 4) * 8;
        const unsigned short* sb = &samp[(wave * 16 + (lane & 15)) * SROW + (lane >> 4) * 8];
#pragma unroll
        for (int s = 0; s < 9; ++s) {
            const bf16x8 bfr = *(const bf16x8*)(sb + s * 32);
            const bf16x8 a0 = *(const bf16x8*)(wb + s * 256);
            const bf16x8 a1 = *(const bf16x8*)(wb + (size_t)16 * KTOT + s * 256);
            acc0 = __builtin_amdgcn_mfma_f32_16x16x32_bf16(a0, bfr, acc0, 0, 0, 0);
            acc1 = __builtin_amdgcn_mfma_f32_16x16x32_bf16(a1, bfr, acc1, 0, 0, 0);
        }
    }
    const int px = wave * 16 + (lane & 15);
    const int wy = ty0 + (px >> 3), wx = tx0 + (px & 7);
#pragma unroll
    for (int j = 0; j < 4; ++j) {
        const int c0 = (lane >> 4) * 4 + j;
        if (c0 < OFFC)
            offs[((size_t)b * OFFC + c0) * HW + wy * WN + wx] = acc0[j] + b_off[c0];
        const int c1 = 16 + c0;
        if (c1 < OFFC)
            offs[((size_t)b * OFFC + c1) * HW + wy * WN + wx] = acc1[j] + b_off[c1];
    }
}

// ---------------- Stage 2: bilinear gather (vectorized) + MFMA GEMM --------
// 512 threads / 8 waves; wave owns 32 cout x 64 px (acc[2][4] f32x4).
__global__ __launch_bounds__(512, 4) void dcn_mfma_kernel(
    const unsigned short* __restrict__ xh, const float* __restrict__ offs,
    const unsigned short* __restrict__ wd_b, const float* __restrict__ bias,
    float* __restrict__ out)
{
    __shared__ unsigned short samp[64 * SROW];   // 37,888 B
    __shared__ uint4  tidx[576];                 //  9,216 B  [kk*64+px] elem offsets
    __shared__ float4 twgt[576];                 //  9,216 B

    const int blk = blockIdx.x;
    const int b = blk >> 6;
    const int tile = blk & 63;
    const int ty0 = (tile >> 3) << 3;
    const int tx0 = (tile & 7) << 3;
    const int t = threadIdx.x;
    const int lane = t & 63;
    const int wave = t >> 6;
    const unsigned short* xb = xh + (size_t)b * HW * CIN;

    for (int i = t; i < 576; i += 512) {
        const int kk = i >> 6, p = i & 63;
        const int oy = ty0 + (p >> 3), ox = tx0 + (p & 7);
        const float offy = offs[((size_t)b * OFFC + 2 * kk) * HW + oy * WN + ox];
        const float offx = offs[((size_t)b * OFFC + 2 * kk + 1) * HW + oy * WN + ox];
        const int ky = kk / 3;
        const float pyf = (float)(oy - 1 + ky) + offy;
        const float pxf = (float)(ox - 1 + (kk - ky * 3)) + offx;
        const float fy0 = floorf(pyf), fx0 = floorf(pxf);
        const int iy0 = (int)fy0, ix0 = (int)fx0;
        const int iy1 = iy0 + 1, ix1 = ix0 + 1;
        const float fy = pyf - fy0, fx = pxf - fx0;
        const float vy0 = ((unsigned)iy0 < HN) ? 1.f : 0.f;
        const float vy1 = ((unsigned)iy1 < HN) ? 1.f : 0.f;
        const float vx0 = ((unsigned)ix0 < WN) ? 1.f : 0.f;
        const float vx1 = ((unsigned)ix1 < WN) ? 1.f : 0.f;
        const int cy0 = min(max(iy0, 0), HN - 1), cy1 = min(max(iy1, 0), HN - 1);
        const int cx0 = min(max(ix0, 0), WN - 1), cx1 = min(max(ix1, 0), WN - 1);
        tidx[i] = make_uint4((unsigned)(cy0 * WN + cx0) * CIN, (unsigned)(cy0 * WN + cx1) * CIN,
                             (unsigned)(cy1 * WN + cx0) * CIN, (unsigned)(cy1 * WN + cx1) * CIN);
        twgt[i] = make_float4((1.f - fy) * (1.f - fx) * vy0 * vx0,
                              (1.f - fy) * fx * vy0 * vx1,
                              fy * (1.f - fx) * vy1 * vx0,
                              fy * fx * vy1 * vx1);
    }

    f32x4 acc[2][4];
#pragma unroll
    for (int i = 0; i < 2; ++i)
#pragma unroll
        for (int j = 0; j < 4; ++j) acc[i][j] = (f32x4){0.f, 0.f, 0.f, 0.f};

    for (int chunk = 0; chunk < NCHUNK; ++chunk) {
        const int ci0 = chunk * CICH;
        __syncthreads();   // covers taps (1st) + prior GEMM readers
        // sampling: 4 vector corner loads -> weighted sum -> pack -> LDS
        for (int id = t; id < 2304; id += 512) {
            const int kk = id >> 8;
            const int px = (id >> 2) & 63;
            const int g = id & 3;
            const uint4 ti = tidx[kk * 64 + px];
            const float4 tw = twgt[kk * 64 + px];
            const unsigned short* base = xb + ci0 + g * 8;
            const bf16x8 A  = *(const bf16x8*)(base + ti.x);
            const bf16x8 Bv = *(const bf16x8*)(base + ti.y);
            const bf16x8 Cv = *(const bf16x8*)(base + ti.z);
            const bf16x8 Dv = *(const bf16x8*)(base + ti.w);
            unsigned r[4];
#pragma unroll
            for (int q = 0; q < 4; ++q) {
                const float v0 = tw.x * bf2f(A[2*q])   + tw.y * bf2f(Bv[2*q])
                               + tw.z * bf2f(Cv[2*q])  + tw.w * bf2f(Dv[2*q]);
                const float v1 = tw.x * bf2f(A[2*q+1]) + tw.y * bf2f(Bv[2*q+1])
                               + tw.z * bf2f(Cv[2*q+1])+ tw.w * bf2f(Dv[2*q+1]);
                r[q] = pk2(v0, v1);
            }
            *(uint4*)&samp[px * SROW + kk * 32 + g * 8] = (uint4){r[0], r[1], r[2], r[3]};
        }
        __syncthreads();
        // GEMM: wave's 2 cout-tiles x 4 px-tiles
        const unsigned short* wb = wd_b + (size_t)(wave * 32 + (lane & 15)) * KTOT + ci0 + (lane >> 4) * 8;
        const unsigned short* sb = &samp[(lane & 15) * SROW + (lane >> 4) * 8];
#pragma unroll
        for (int s = 0; s < 9; ++s) {
            bf16x8 afr[2], bfr[4];
            afr[0] = *(const bf16x8*)(wb + s * 256);
            afr[1] = *(const bf16x8*)(wb + (size_t)16 * KTOT + s * 256);
#pragma unroll
            for (int pt = 0; pt < 4; ++pt)
                bfr[pt] = *(const bf16x8*)(sb + pt * 16 * SROW + s * 32);
#pragma unroll
            for (int ct = 0; ct < 2; ++ct)
#pragma unroll
                for (int pt = 0; pt < 4; ++pt)
                    acc[ct][pt] = __builtin_amdgcn_mfma_f32_16x16x32_bf16(afr[ct], bfr[pt], acc[ct][pt], 0, 0, 0);
        }
    }

#pragma unroll
    for (int ct = 0; ct < 2; ++ct) {
#pragma unroll
        for (int pt = 0; pt < 4; ++pt) {
            const int px = pt * 16 + (lane & 15);
            const int wy = ty0 + (px >> 3), wx = tx0 + (px & 7);
#pragma unroll
            for (int j = 0; j < 4; ++j) {
                const int cout = wave * 32 + ct * 16 + (lane >> 4) * 4 + j;
                out[((size_t)b * COUT + cout) * HW + wy * WN + wx] = acc[ct][pt][j] + bias[cout];
            }
        }
    }
}

extern "C" void kernel_launch(void* const* d_in, const int* in_sizes, int n_in,
                              void* d_out, int out_size, void* d_ws, size_t ws_size,
                              hipStream_t stream) {
    const float* x     = (const float*)d_in[0];
    const float* w_off = (const float*)d_in[1];
    const float* b_off = (const float*)d_in[2];
    const float* w_dcn = (const float*)d_in[3];
    const float* b_dcn = (const float*)d_in[4];
    float* out = (float*)d_out;

    // ws: offs fp32 2,359,296 | wd_b 1,179,648 | wo_b 147,456 | xh 16,777,216  = 20.46 MB
    float* offs          = (float*)d_ws;
    unsigned short* wd_b = (unsigned short*)((char*)d_ws + 2359296);
    unsigned short* wo_b = (unsigned short*)((char*)d_ws + 2359296 + 1179648);
    unsigned short* xh   = (unsigned short*)((char*)d_ws + 2359296 + 1179648 + 147456);

    prep_kernel<<<800, 256, 0, stream>>>(x, w_dcn, w_off, xh, wd_b, wo_b);
    offs_mfma_kernel<<<512, 256, 0, stream>>>(xh, wo_b, b_off, offs);
    dcn_mfma_kernel<<<512, 512, 0, stream>>>(xh, offs, wd_b, b_dcn, out);
}

// Round 7
// 234.571 us; speedup vs baseline: 4.0064x; 1.0035x over previous
//
#include <hip/hip_runtime.h>

#define HN 64
#define WN 64
#define HW 4096
#define CIN 256
#define COUT 256
#define NKK 9
#define OFFC 18
#define KTOT 2304          // 256*9, kk-major: k = kk*256 + c
#define CICH 32
#define KCH 288            // 9 kk * 32 c per chunk
#define SROW 296           // samp row stride bf16 (288+8 pad, 592 B)
#define NCHUNK 8

typedef __attribute__((ext_vector_type(8))) short bf16x8;
typedef __attribute__((ext_vector_type(4))) float f32x4;

// fp32 -> bf16 round-to-nearest-even (finite inputs)
static __device__ __forceinline__ unsigned short f2bf(float f) {
    unsigned u = __float_as_uint(f);
    return (unsigned short)((u + 0x7FFFu + ((u >> 16) & 1u)) >> 16);
}
static __device__ __forceinline__ unsigned pk2(float a, float b) {
    return (unsigned)f2bf(a) | ((unsigned)f2bf(b) << 16);
}
static __device__ __forceinline__ float bf2f(short s) {
    return __uint_as_float(((unsigned)(unsigned short)s) << 16);
}

// ---------------- Stage 0: prep — x -> NHWC bf16 + weight repack -----------
__global__ __launch_bounds__(256) void prep_kernel(
    const float* __restrict__ x, const float* __restrict__ w_dcn,
    const float* __restrict__ w_off, unsigned short* __restrict__ xh,
    unsigned short* __restrict__ wd_b, unsigned short* __restrict__ wo_b)
{
    const int blk = blockIdx.x;
    const int t = threadIdx.x;
    if (blk < 512) {
        __shared__ unsigned short lds[64 * 264];
        const int b = blk >> 6;
        const int row = blk & 63;
        const int p = t & 63;
        const int cb = (t >> 6) * 8;
        const float* xp = x + (size_t)b * CIN * HW + row * WN + p;
#pragma unroll
        for (int i = 0; i < 8; ++i) {
            const int c0 = cb + i * 32;
            float v[8];
#pragma unroll
            for (int j = 0; j < 8; ++j)
                v[j] = xp[(size_t)(c0 + j) * HW];
            uint4 o = { pk2(v[0],v[1]), pk2(v[2],v[3]), pk2(v[4],v[5]), pk2(v[6],v[7]) };
            *(uint4*)&lds[p * 264 + c0] = o;
        }
        __syncthreads();
        unsigned short* op = xh + ((size_t)b * HW + row * WN) * CIN;
#pragma unroll
        for (int i = 0; i < 8; ++i) {
            const int idx = i * 256 + t;
            const int cg = idx & 31, pp = idx >> 5;
            *(uint4*)(op + (size_t)pp * CIN + cg * 8) = *(const uint4*)&lds[pp * 264 + cg * 8];
        }
    } else if (blk < 768) {
        const int cout = blk - 512;
        for (int id = t; id < 288; id += 256) {
            const int k = id * 8;
            const int kk = k >> 8, c0 = k & 255;
            const float* wp = w_dcn + (size_t)cout * KTOT + kk;
            float v[8];
#pragma unroll
            for (int j = 0; j < 8; ++j) v[j] = wp[(size_t)(c0 + j) * NKK];
            uint4 o = { pk2(v[0],v[1]), pk2(v[2],v[3]), pk2(v[4],v[5]), pk2(v[6],v[7]) };
            *(uint4*)(wd_b + (size_t)cout * KTOT + k) = o;
        }
    } else {
        const int r = blk - 768;
        for (int id = t; id < 288; id += 256) {
            const int k = id * 8;
            const int kk = k >> 8, c0 = k & 255;
            uint4 o = {0u, 0u, 0u, 0u};
            if (r < OFFC) {
                const float* wp = w_off + (size_t)r * KTOT + kk;
                float v[8];
#pragma unroll
                for (int j = 0; j < 8; ++j) v[j] = wp[(size_t)(c0 + j) * NKK];
                o = (uint4){ pk2(v[0],v[1]), pk2(v[2],v[3]), pk2(v[4],v[5]), pk2(v[6],v[7]) };
            }
            *(uint4*)(wo_b + (size_t)r * KTOT + k) = o;
        }
    }
}

// ---------------- Stage 1: offsets conv — LDS-free direct-MFMA -------------
// 256 thr / 4 waves; wave owns px-tile (16 px); B frags loaded straight from
// global xh (16B predicated loads). No LDS, no barriers.
__global__ __launch_bounds__(256) void offs_mfma_kernel(
    const unsigned short* __restrict__ xh, const unsigned short* __restrict__ wo_b,
    const float* __restrict__ b_off, float* __restrict__ offs)
{
    const int blk = blockIdx.x;
    const int b = blk & 7;            // XCD swizzle: batch -> XCD
    const int tile = blk >> 3;
    const int ty0 = (tile >> 3) << 3;
    const int tx0 = (tile & 7) << 3;
    const int t = threadIdx.x;
    const int lane = t & 63;
    const int wave = t >> 6;
    const int pxl = wave * 16 + (lane & 15);
    const int kq8 = (lane >> 4) * 8;
    const int oy = ty0 + (pxl >> 3);
    const int ox = tx0 + (pxl & 7);
    const unsigned short* xb = xh + (size_t)b * HW * CIN + kq8;
    const unsigned short* wrow = wo_b + (size_t)(lane & 15) * KTOT + kq8;

    f32x4 acc0 = {0.f,0.f,0.f,0.f}, acc1 = {0.f,0.f,0.f,0.f};
#pragma unroll
    for (int kk = 0; kk < 9; ++kk) {
        const int yy = oy + kk / 3 - 1;
        const int xx = ox + kk % 3 - 1;
        const bool valid = ((unsigned)yy < HN) && ((unsigned)xx < WN);
        const unsigned short* bp = xb + (size_t)(yy * WN + xx) * CIN;
        const unsigned short* wp = wrow + kk * 256;
#pragma unroll
        for (int s = 0; s < 8; ++s) {
            const bf16x8 bfr = valid ? *(const bf16x8*)(bp + s * 32)
                                     : (bf16x8){0,0,0,0,0,0,0,0};
            const bf16x8 a0 = *(const bf16x8*)(wp + s * 32);
            const bf16x8 a1 = *(const bf16x8*)(wp + (size_t)16 * KTOT + s * 32);
            acc0 = __builtin_amdgcn_mfma_f32_16x16x32_bf16(a0, bfr, acc0, 0, 0, 0);
            acc1 = __builtin_amdgcn_mfma_f32_16x16x32_bf16(a1, bfr, acc1, 0, 0, 0);
        }
    }
    const int wy = ty0 + (pxl >> 3), wx = tx0 + (pxl & 7);
#pragma unroll
    for (int j = 0; j < 4; ++j) {
        const int c0 = (lane >> 4) * 4 + j;
        if (c0 < OFFC)
            offs[((size_t)b * OFFC + c0) * HW + wy * WN + wx] = acc0[j] + b_off[c0];
        const int c1 = 16 + c0;
        if (c1 < OFFC)
            offs[((size_t)b * OFFC + c1) * HW + wy * WN + wx] = acc1[j] + b_off[c1];
    }
}

// ---------------- Stage 2: bilinear gather + MFMA GEMM ---------------------
// 1024 thr / 16 waves; wave = 16 couts x 64 px (acc[4] f32x4 = 16 VGPR).
// 2 blocks/CU -> 32 waves/CU target.
static __device__ __forceinline__ void sample_one(
    int id, const unsigned short* __restrict__ xb, int ci0,
    const uint4* __restrict__ tidx, const float4* __restrict__ twgt,
    unsigned short* __restrict__ samp)
{
    const int kk = id >> 8;
    const int px = (id >> 2) & 63;
    const int g  = id & 3;
    const uint4  ti = tidx[kk * 64 + px];
    const float4 tw = twgt[kk * 64 + px];
    const unsigned short* base = xb + ci0 + g * 8;
    const bf16x8 A  = *(const bf16x8*)(base + ti.x);
    const bf16x8 Bv = *(const bf16x8*)(base + ti.y);
    float v[8];
#pragma unroll
    for (int e = 0; e < 8; ++e) v[e] = tw.x * bf2f(A[e]) + tw.y * bf2f(Bv[e]);
    const bf16x8 Cv = *(const bf16x8*)(base + ti.z);
    const bf16x8 Dv = *(const bf16x8*)(base + ti.w);
#pragma unroll
    for (int e = 0; e < 8; ++e) v[e] += tw.z * bf2f(Cv[e]) + tw.w * bf2f(Dv[e]);
    uint4 o = { pk2(v[0],v[1]), pk2(v[2],v[3]), pk2(v[4],v[5]), pk2(v[6],v[7]) };
    *(uint4*)&samp[px * SROW + kk * 32 + g * 8] = o;
}

__global__ __launch_bounds__(1024, 8) void dcn_mfma_kernel(
    const unsigned short* __restrict__ xh, const float* __restrict__ offs,
    const unsigned short* __restrict__ wd_b, const float* __restrict__ bias,
    float* __restrict__ out)
{
    __shared__ unsigned short samp[64 * SROW];   // 37,888 B
    __shared__ uint4  tidx[576];                 //  9,216 B
    __shared__ float4 twgt[576];                 //  9,216 B

    const int blk = blockIdx.x;
    const int b = blk & 7;            // XCD swizzle
    const int tile = blk >> 3;
    const int ty0 = (tile >> 3) << 3;
    const int tx0 = (tile & 7) << 3;
    const int t = threadIdx.x;
    const int lane = t & 63;
    const int wave = t >> 6;
    const unsigned short* xb = xh + (size_t)b * HW * CIN;

    // tap precompute
    for (int i = t; i < 576; i += 1024) {
        const int kk = i >> 6, p = i & 63;
        const int oy = ty0 + (p >> 3), ox = tx0 + (p & 7);
        const float offy = offs[((size_t)b * OFFC + 2 * kk) * HW + oy * WN + ox];
        const float offx = offs[((size_t)b * OFFC + 2 * kk + 1) * HW + oy * WN + ox];
        const int ky = kk / 3;
        const float pyf = (float)(oy - 1 + ky) + offy;
        const float pxf = (float)(ox - 1 + (kk - ky * 3)) + offx;
        const float fy0 = floorf(pyf), fx0 = floorf(pxf);
        const int iy0 = (int)fy0, ix0 = (int)fx0;
        const int iy1 = iy0 + 1, ix1 = ix0 + 1;
        const float fy = pyf - fy0, fx = pxf - fx0;
        const float vy0 = ((unsigned)iy0 < HN) ? 1.f : 0.f;
        const float vy1 = ((unsigned)iy1 < HN) ? 1.f : 0.f;
        const float vx0 = ((unsigned)ix0 < WN) ? 1.f : 0.f;
        const float vx1 = ((unsigned)ix1 < WN) ? 1.f : 0.f;
        const int cy0 = min(max(iy0, 0), HN - 1), cy1 = min(max(iy1, 0), HN - 1);
        const int cx0 = min(max(ix0, 0), WN - 1), cx1 = min(max(ix1, 0), WN - 1);
        tidx[i] = make_uint4((unsigned)(cy0 * WN + cx0) * CIN, (unsigned)(cy0 * WN + cx1) * CIN,
                             (unsigned)(cy1 * WN + cx0) * CIN, (unsigned)(cy1 * WN + cx1) * CIN);
        twgt[i] = make_float4((1.f - fy) * (1.f - fx) * vy0 * vx0,
                              (1.f - fy) * fx * vy0 * vx1,
                              fy * (1.f - fx) * vy1 * vx0,
                              fy * fx * vy1 * vx1);
    }

    f32x4 acc0 = {0.f,0.f,0.f,0.f}, acc1 = {0.f,0.f,0.f,0.f};
    f32x4 acc2 = {0.f,0.f,0.f,0.f}, acc3 = {0.f,0.f,0.f,0.f};

    for (int chunk = 0; chunk < NCHUNK; ++chunk) {
        const int ci0 = chunk * CICH;
        __syncthreads();   // covers taps (1st) + prior GEMM readers
        sample_one(t,        xb, ci0, tidx, twgt, samp);
        sample_one(t + 1024, xb, ci0, tidx, twgt, samp);
        if (t < 256) sample_one(t + 2048, xb, ci0, tidx, twgt, samp);
        __syncthreads();
        const unsigned short* wb = wd_b + (size_t)(wave * 16 + (lane & 15)) * KTOT
                                 + ci0 + (lane >> 4) * 8;
        const unsigned short* sb = &samp[(lane & 15) * SROW + (lane >> 4) * 8];
#pragma unroll
        for (int s = 0; s < 9; ++s) {
            const bf16x8 a    = *(const bf16x8*)(wb + s * 256);
            const bf16x8 bfr0 = *(const bf16x8*)(sb + s * 32);
            const bf16x8 bfr1 = *(const bf16x8*)(sb + 16 * SROW + s * 32);
            const bf16x8 bfr2 = *(const bf16x8*)(sb + 32 * SROW + s * 32);
            const bf16x8 bfr3 = *(const bf16x8*)(sb + 48 * SROW + s * 32);
            acc0 = __builtin_amdgcn_mfma_f32_16x16x32_bf16(a, bfr0, acc0, 0, 0, 0);
            acc1 = __builtin_amdgcn_mfma_f32_16x16x32_bf16(a, bfr1, acc1, 0, 0, 0);
            acc2 = __builtin_amdgcn_mfma_f32_16x16x32_bf16(a, bfr2, acc2, 0, 0, 0);
            acc3 = __builtin_amdgcn_mfma_f32_16x16x32_bf16(a, bfr3, acc3, 0, 0, 0);
        }
    }

    // epilogue
    const int row4 = (lane >> 4) * 4;
    float bv[4];
#pragma unroll
    for (int j = 0; j < 4; ++j) bv[j] = bias[wave * 16 + row4 + j];
    const f32x4 av[4] = {acc0, acc1, acc2, acc3};
#pragma unroll
    for (int pt = 0; pt < 4; ++pt) {
        const int px = pt * 16 + (lane & 15);
        const int wy = ty0 + (px >> 3), wx = tx0 + (px & 7);
        float* op = out + ((size_t)b * COUT + wave * 16 + row4) * HW + wy * WN + wx;
#pragma unroll
        for (int j = 0; j < 4; ++j)
            op[(size_t)j * HW] = av[pt][j] + bv[j];
    }
}

extern "C" void kernel_launch(void* const* d_in, const int* in_sizes, int n_in,
                              void* d_out, int out_size, void* d_ws, size_t ws_size,
                              hipStream_t stream) {
    const float* x     = (const float*)d_in[0];
    const float* w_off = (const float*)d_in[1];
    const float* b_off = (const float*)d_in[2];
    const float* w_dcn = (const float*)d_in[3];
    const float* b_dcn = (const float*)d_in[4];
    float* out = (float*)d_out;

    // ws: offs fp32 2,359,296 | wd_b 1,179,648 | wo_b 147,456 | xh 16,777,216
    float* offs          = (float*)d_ws;
    unsigned short* wd_b = (unsigned short*)((char*)d_ws + 2359296);
    unsigned short* wo_b = (unsigned short*)((char*)d_ws + 2359296 + 1179648);
    unsigned short* xh   = (unsigned short*)((char*)d_ws + 2359296 + 1179648 + 147456);

    prep_kernel<<<800, 256, 0, stream>>>(x, w_dcn, w_off, xh, wd_b, wo_b);
    offs_mfma_kernel<<<512, 256, 0, stream>>>(xh, wo_b, b_off, offs);
    dcn_mfma_kernel<<<512, 1024, 0, stream>>>(xh, offs, wd_b, b_dcn, out);
}